// Round 17
// baseline (2021.798 us; speedup 1.0000x reference)
//
#include <hip/hip_runtime.h>
#include <math.h>

// ---------------- constants ----------------
static constexpr int B_   = 128;
static constexpr int ORG_ = 4;
static constexpr int L_   = 2048;
static constexpr int C1_  = 128;
static constexpr int C2_  = 64;
static constexpr int NG_  = 8;
static constexpr int VQD_ = 64;
static constexpr int VQN_ = 1024;
static constexpr long PTS_ = (long)B_ * (L_ / 4);   // 65536 max points

typedef __attribute__((ext_vector_type(8))) short bf16x8;
typedef __attribute__((ext_vector_type(4))) float f32x4;

__device__ __forceinline__ float selu_f(float x) {
    const float scale = 1.0507009873554805f;
    const float alpha = 1.6732632423543772f;
    return scale * (x > 0.f ? x : alpha * expm1f(x));
}
__device__ __forceinline__ unsigned short f2bf(float x) {
    unsigned u = __float_as_uint(x);
    u = (u + 0x7FFFu + ((u >> 16) & 1u)) >> 16;
    return (unsigned short)u;
}
__device__ __forceinline__ float bf2f(unsigned short u) {
    return __uint_as_float((unsigned)u << 16);
}

// ---------------- weight prep (f32 direct-conv layout) ----------------
__global__ void wprep_kernel(const float* __restrict__ w, float* __restrict__ wT,
                             int CO, int cig, int K, int so, int si, int sk, int koff)
{
    int idx = blockIdx.x * 256 + threadIdx.x;
    int total = cig * K * CO;
    if (idx >= total) return;
    int o = idx % CO;
    int r = idx / CO;
    int i = r / K, k = r % K;
    wT[idx] = w[(long)o * so + (long)i * si + (long)k * sk + koff];
}

// ---------------- weight prep (MFMA bf16 layout) for tconv 128x128 K=5 ----------------
__global__ void wprep_mfma_kernel(const float* __restrict__ w, unsigned short* __restrict__ wb)
{
    int idx = blockIdx.x * 256 + threadIdx.x;   // total 81920
    if (idx >= 5 * 16 * 128 * 8) return;
    int j  = idx & 7;
    int o  = (idx >> 3) & 127;
    int kk = idx >> 10;          // 0..79
    int ig = kk & 3, ic = (kk >> 2) & 3, k = kk >> 4;
    int i  = ic * 32 + ig * 8 + j;
    wb[idx] = f2bf(w[(long)i * (128 * 5) + o * 5 + (4 - k)]);
}

__global__ void fill_kernel(float* p, float v, int n)
{
    int i = blockIdx.x * 256 + threadIdx.x;
    if (i < n) p[i] = v;
}

// ---------------- LDS-tiled f32 conv with optional fused input transform ----------------
// VQ=1: per-slot argmin of score=fma(acc,scale,bias) -> vbest/vbj; blockIdx.z selects the
//       256-code slice (weights/bias/jbase/outputs offset by z).
template<int K, int CO, int NTHR, int TT, int OT, int VQ>
__global__ __launch_bounds__(NTHR) void conv_tile_kernel(
    const float* __restrict__ in, const float* __restrict__ wT,
    const float* __restrict__ scale, const float* __restrict__ bias,
    float* __restrict__ out,
    int CI, int T, int cig, int cog,
    const float* __restrict__ ist, const float* __restrict__ ig,
    const float* __restrict__ ibt, int icpg, int iselu,
    const float* __restrict__ res,
    float* __restrict__ vbest, int* __restrict__ vbj, int jbase, long vstride)
{
    constexpr int P    = (K - 1) / 2;
    constexpr int SPAN = TT + K - 1;
    constexpr int RS   = (SPAN + 3) & ~3;
    constexpr int NO   = CO / OT;
    constexpr int NT   = (CO * TT) / (NTHR * OT);
    constexpr int XW   = NT + K - 1;
    extern __shared__ float lds[];

    if constexpr (VQ) {
        const int z = blockIdx.z;
        wT    += (long)z * cig * K * CO;
        bias  += (long)z * CO;
        vbest += (long)z * vstride;
        vbj   += (long)z * vstride;
        jbase += z * CO;
    }

    const int tile = blockIdx.x;
    const int b    = blockIdx.y;
    const int t0g  = tile * TT;
    const float* inb = in + (long)b * CI * T;

    for (int idx = threadIdx.x; idx < CI * SPAN; idx += NTHR) {
        int c = idx / SPAN, j = idx % SPAN;
        int tt = t0g + j - P;
        float v = 0.f;
        if (tt >= 0 && tt < T) {
            v = inb[(long)c * T + tt];
            if (ist) {
                const float* s = &ist[2 * (b * NG_ + c / icpg)];
                v = (v - s[0]) * s[1] * ig[c] + ibt[c];
                if (res) v += res[((long)b * CI + c) * T + tt];
                if (iselu) v = selu_f(v);
            }
        }
        lds[c * RS + j] = v;
    }
    __syncthreads();

    const int o0   = (threadIdx.x % NO) * OT;
    const int slot = threadIdx.x / NO;
    const int t0   = slot * NT;
    const int g    = o0 / cog;
    const float* wrow = wT + o0;

    float acc[OT][NT];
#pragma unroll
    for (int oo = 0; oo < OT; ++oo)
#pragma unroll
        for (int u = 0; u < NT; ++u) acc[oo][u] = 0.f;

#pragma unroll 4
    for (int i = 0; i < cig; ++i) {
        const int irow = g * cig + i;
        float xin[(XW + 3) & ~3];
        if constexpr (NT % 4 == 0) {
            constexpr int X4 = (XW + 3) / 4;
            const float4* l4 = reinterpret_cast<const float4*>(&lds[irow * RS + t0]);
#pragma unroll
            for (int j = 0; j < X4; ++j) {
                float4 v = l4[j];
                xin[4 * j]     = v.x;
                xin[4 * j + 1] = v.y;
                xin[4 * j + 2] = v.z;
                xin[4 * j + 3] = v.w;
            }
        } else {
#pragma unroll
            for (int j = 0; j < XW; ++j) xin[j] = lds[irow * RS + t0 + j];
        }
        float wk[OT][K];
#pragma unroll
        for (int oo = 0; oo < OT; ++oo)
#pragma unroll
            for (int k = 0; k < K; ++k) wk[oo][k] = wrow[(i * K + k) * CO + oo];
#pragma unroll
        for (int oo = 0; oo < OT; ++oo)
#pragma unroll
            for (int u = 0; u < NT; ++u)
#pragma unroll
                for (int k = 0; k < K; ++k)
                    acc[oo][u] = fmaf(xin[u + k], wk[oo][k], acc[oo][u]);
    }

    if constexpr (VQ) {
        constexpr int RW = (NO >= 64) ? 64 : 32;   // reduce width: one t-slot per RW lanes
        const int lane = threadIdx.x & 63;
#pragma unroll
        for (int u = 0; u < NT; ++u) {
            float bv = 3.4e38f;
            int bj = 0;
#pragma unroll
            for (int oo = 0; oo < OT; ++oo) {
                const int o = o0 + oo;
                float sv = fmaf(acc[oo][u], scale[o], bias[o]);
                if (sv < bv) { bv = sv; bj = jbase + o; }
            }
#pragma unroll
            for (int off = 1; off < RW; off <<= 1) {
                float v2 = __shfl_xor(bv, off);
                int   j2 = __shfl_xor(bj, off);
                if (v2 < bv || (v2 == bv && j2 < bj)) { bv = v2; bj = j2; }
            }
            if ((lane & (RW - 1)) == 0) {
                long n = (long)b * T + t0g + t0 + u;
                vbest[n] = bv;
                vbj[n]   = bj;
            }
        }
    } else {
#pragma unroll
        for (int oo = 0; oo < OT; ++oo) {
            const int o = o0 + oo;
            const float sc = scale ? scale[o] : 1.f;
            const float bi = bias  ? bias[o]  : 0.f;
            float* ob = out + ((long)b * CO + o) * T + t0g + t0;
#pragma unroll
            for (int u = 0; u < NT; ++u) ob[u] = acc[oo][u] * sc + bi;
        }
    }
}

// ---------------- deres0 epilogue conv, ci-split: bf16 in/res, f32 partials ----------------
// NOTE: the cc-loop must NOT be unrolled/pipelined — the wave-private row[] window is
// cross-lane wave-synchronous (write-then-read each iteration, no barrier). r16 regression.
__global__ __launch_bounds__(256) void conv_epi7_kernel(
    const unsigned short* __restrict__ in, const float* __restrict__ wT,
    float* __restrict__ pbuf, int T, int Bc,
    const float* __restrict__ ist, const float* __restrict__ ig_,
    const float* __restrict__ ibt, int icpg,
    const unsigned short* __restrict__ res)
{
    __shared__ float wlds[32 * 7 * 4];
    __shared__ float rows[4][80];

    const int z   = blockIdx.z;
    const int ci0 = z * 32;

    for (int idx = threadIdx.x; idx < 32 * 7 * 4; idx += 256)
        wlds[idx] = wT[ci0 * 7 * 4 + idx];
    __syncthreads();

    const int wid  = threadIdx.x >> 6;
    const int lane = threadIdx.x & 63;
    const int b    = blockIdx.y;
    const int t0w  = blockIdx.x * 256 + wid * 64;
    const int t    = t0w + lane;
    float* row = rows[wid];
    const long base = (long)b * 128 * T;

    float acc0 = 0.f, acc1 = 0.f, acc2 = 0.f, acc3 = 0.f;

    for (int cc = 0; cc < 32; ++cc) {
        const int ci = ci0 + cc;
        const float* s = &ist[2 * (b * NG_ + ci / icpg)];
        const float mu = s[0], rs = s[1];
        const float gc = ig_[ci], bc = ibt[ci];
        const long cbase = base + (long)ci * T;

        float v = bf2f(in[cbase + t]);
        v = (v - mu) * rs * gc + bc;
        v += bf2f(res[cbase + t]);
        v = selu_f(v);
        row[3 + lane] = v;

        if (lane < 3 || lane >= 61) {
            int th   = (lane < 3) ? (t0w - 3 + lane) : (t0w + 3 + lane);
            int ridx = (lane < 3) ? lane : (lane + 6);
            float h = 0.f;
            if (th >= 0 && th < T) {
                h = bf2f(in[cbase + th]);
                h = (h - mu) * rs * gc + bc;
                h += bf2f(res[cbase + th]);
                h = selu_f(h);
            }
            row[ridx] = h;
        }

        float xin[7];
#pragma unroll
        for (int j = 0; j < 7; ++j) xin[j] = row[lane + j];
#pragma unroll
        for (int k = 0; k < 7; ++k) {
            float4 w4 = *(const float4*)&wlds[(cc * 7 + k) * 4];
            acc0 = fmaf(xin[k], w4.x, acc0);
            acc1 = fmaf(xin[k], w4.y, acc1);
            acc2 = fmaf(xin[k], w4.z, acc2);
            acc3 = fmaf(xin[k], w4.w, acc3);
        }
    }

    const long half = (long)Bc * 4 * T;
    float* pb = pbuf + (long)z * half + ((long)b * 4) * T + t;
    pb[0 * T] = acc0;
    pb[1 * T] = acc1;
    pb[2 * T] = acc2;
    pb[3 * T] = acc3;
}

// combine 4 ci-partials + bias -> out
__global__ void epi_comb_kernel(const float* __restrict__ pbuf,
                                const float* __restrict__ bias,
                                float* __restrict__ out, int T, int Bc, long total)
{
    const long half = (long)Bc * 4 * T;
    for (long idx = blockIdx.x * (long)blockDim.x + threadIdx.x; idx < total;
         idx += (long)gridDim.x * blockDim.x) {
        const int o = (int)((idx / T) & 3);
        float v = ((pbuf[idx] + pbuf[half + idx]) + pbuf[2 * half + idx])
                  + pbuf[3 * half + idx];
        out[idx] = v + bias[o];
    }
}

// ---------------- MFMA bf16 conv v3: bf16 in, bf16 out ----------------
// Block 256 thr / 4 waves; tile 64t x 128o (18.5 KB LDS).
// Wave partition by OUTPUT CHANNEL: wave w owns ot in {2w, 2w+1} across all four
// 16-t m-subtiles -> no weight duplication across waves.
__global__ __launch_bounds__(256) void conv_mfma5_kernel(
    const unsigned short* __restrict__ in, const unsigned short* __restrict__ wb,
    unsigned short* __restrict__ out, int T,
    const float* __restrict__ ist, const float* __restrict__ ig_,
    const float* __restrict__ ibt, int icpg)
{
    constexpr int SPAN = 68, RSI = 136;
    __shared__ unsigned short xlds[SPAN * RSI];   // 18.5 KB

    const int t0g = blockIdx.x * 64;
    const int b   = blockIdx.y;
    const unsigned short* inb = in + (long)b * 128 * T;

    for (int idx = threadIdx.x; idx < 128 * SPAN; idx += 256) {
        int i = idx / SPAN, j = idx % SPAN;
        int tt = t0g + j - 2;
        unsigned short raw = 0;
        if (tt >= 0 && tt < T) {
            raw = inb[(long)i * T + tt];
            if (ist) {
                const float* s = &ist[2 * (b * NG_ + i / icpg)];
                float v = selu_f((bf2f(raw) - s[0]) * s[1] * ig_[i] + ibt[i]);
                raw = f2bf(v);
            }
        }
        xlds[j * RSI + i] = raw;
    }
    __syncthreads();

    const int lane = threadIdx.x & 63;
    const int wid  = threadIdx.x >> 6;   // wave owns ot = {2*wid, 2*wid+1}
    const int mr   = lane & 15;
    const int kg   = lane >> 4;

    f32x4 acc[4][2];
#pragma unroll
    for (int m = 0; m < 4; ++m)
#pragma unroll
        for (int oo = 0; oo < 2; ++oo) acc[m][oo] = (f32x4){0.f, 0.f, 0.f, 0.f};

#pragma unroll
    for (int k = 0; k < 5; ++k) {
#pragma unroll
        for (int ic = 0; ic < 4; ++ic) {
            bf16x8 a[4];
#pragma unroll
            for (int m = 0; m < 4; ++m)
                a[m] = *(const bf16x8*)&xlds[(m * 16 + mr + k) * RSI + ic * 32 + kg * 8];
            const unsigned short* wp = wb + (((k * 16 + ic * 4 + kg) * 128) + mr) * 8;
#pragma unroll
            for (int oo = 0; oo < 2; ++oo) {
                const int ot = wid * 2 + oo;
                bf16x8 bfr = *(const bf16x8*)(wp + ot * 16 * 8);
#pragma unroll
                for (int m = 0; m < 4; ++m)
                    acc[m][oo] = __builtin_amdgcn_mfma_f32_16x16x32_bf16(a[m], bfr, acc[m][oo], 0, 0, 0);
            }
        }
    }

#pragma unroll
    for (int m = 0; m < 4; ++m) {
#pragma unroll
        for (int oo = 0; oo < 2; ++oo) {
            const int ot = wid * 2 + oo;
            int o = ot * 16 + mr;
            ushort4 v;
            v.x = f2bf(acc[m][oo][0]);
            v.y = f2bf(acc[m][oo][1]);
            v.z = f2bf(acc[m][oo][2]);
            v.w = f2bf(acc[m][oo][3]);
            *(ushort4*)&out[((long)b * 128 + o) * T + t0g + m * 16 + kg * 4] = v;
        }
    }
}

// ---------------- GroupNorm stats (f32) ----------------
__global__ __launch_bounds__(256) void gn_stats_kernel(
    const float* __restrict__ x, float* __restrict__ stats,
    int C, int T, int G)
{
    const int bg = blockIdx.x;
    const int cpg = C / G;
    const int b = bg / G, g = bg % G;
    const float* base = x + ((long)b * C + (long)g * cpg) * T;
    const long n4 = (long)cpg * T / 4;
    const float4* b4 = (const float4*)base;
    float s = 0.f, ss = 0.f;
    for (long i = threadIdx.x; i < n4; i += blockDim.x) {
        float4 v = b4[i];
        s += v.x + v.y + v.z + v.w;
        ss += v.x * v.x + v.y * v.y + v.z * v.z + v.w * v.w;
    }
#pragma unroll
    for (int off = 32; off; off >>= 1) {
        s  += __shfl_down(s, off);
        ss += __shfl_down(ss, off);
    }
    __shared__ float sh_s[4], sh_ss[4];
    const int wid = threadIdx.x >> 6, lane = threadIdx.x & 63;
    if (lane == 0) { sh_s[wid] = s; sh_ss[wid] = ss; }
    __syncthreads();
    if (threadIdx.x == 0) {
        float S = 0.f, SS = 0.f;
        for (int i = 0; i < 4; ++i) { S += sh_s[i]; SS += sh_ss[i]; }
        float inv_n = 1.f / (float)((long)cpg * T);
        float mu  = S * inv_n;
        float var = SS * inv_n - mu * mu;
        stats[2 * bg]     = mu;
        stats[2 * bg + 1] = rsqrtf(var + 1e-5f);
    }
}

// ---------------- GroupNorm stats (bf16 input) ----------------
__global__ __launch_bounds__(256) void gn_stats_bf16_kernel(
    const unsigned short* __restrict__ x, float* __restrict__ stats,
    int C, int T, int G)
{
    const int bg = blockIdx.x;
    const int cpg = C / G;
    const int b = bg / G, g = bg % G;
    const unsigned short* base = x + ((long)b * C + (long)g * cpg) * T;
    const long n8 = (long)cpg * T / 8;
    const uint4* b8 = (const uint4*)base;
    float s = 0.f, ss = 0.f;
    for (long i = threadIdx.x; i < n8; i += blockDim.x) {
        uint4 v = b8[i];
        unsigned ws[4] = {v.x, v.y, v.z, v.w};
#pragma unroll
        for (int q = 0; q < 4; ++q) {
            float f0 = __uint_as_float(ws[q] << 16);
            float f1 = __uint_as_float(ws[q] & 0xFFFF0000u);
            s += f0 + f1;
            ss += f0 * f0 + f1 * f1;
        }
    }
#pragma unroll
    for (int off = 32; off; off >>= 1) {
        s  += __shfl_down(s, off);
        ss += __shfl_down(ss, off);
    }
    __shared__ float sh_s[4], sh_ss[4];
    const int wid = threadIdx.x >> 6, lane = threadIdx.x & 63;
    if (lane == 0) { sh_s[wid] = s; sh_ss[wid] = ss; }
    __syncthreads();
    if (threadIdx.x == 0) {
        float S = 0.f, SS = 0.f;
        for (int i = 0; i < 4; ++i) { S += sh_s[i]; SS += sh_ss[i]; }
        float inv_n = 1.f / (float)((long)cpg * T);
        float mu  = S * inv_n;
        float var = SS * inv_n - mu * mu;
        stats[2 * bg]     = mu;
        stats[2 * bg + 1] = rsqrtf(var + 1e-5f);
    }
}

// ---------------- fused: out = maxpool2( selu( T1(x) + T2(r) ) ) (f32, encoder) ----------------
__global__ __launch_bounds__(256) void pool_fused_kernel(
    const float* __restrict__ x, const float* __restrict__ xst,
    const float* __restrict__ xg, const float* __restrict__ xb, int xcpg,
    const float* __restrict__ r, const float* __restrict__ rst,
    const float* __restrict__ rg, const float* __restrict__ rb, int rcpg, int rselu,
    float* __restrict__ out, int C, int Tout, long total)
{
    for (long idx = blockIdx.x * (long)blockDim.x + threadIdx.x; idx < total;
         idx += (long)gridDim.x * blockDim.x) {
        const int to = (int)(idx % Tout);
        const int c  = (int)((idx / Tout) % C);
        const int b  = (int)(idx / ((long)Tout * C));
        const long base = ((long)b * C + c) * (2 * Tout);
        const float* sx = &xst[2 * (b * NG_ + c / xcpg)];
        const float xgc = sx[1] * xg[c], xbc = xb[c] - sx[0] * sx[1] * xg[c];
        float rgc = 1.f, rbc = 0.f;
        if (rst) {
            const float* sr = &rst[2 * (b * NG_ + c / rcpg)];
            rgc = sr[1] * rg[c]; rbc = rb[c] - sr[0] * sr[1] * rg[c];
        }
        float f[2];
#pragma unroll
        for (int q = 0; q < 2; ++q) {
            long t = base + 2 * to + q;
            float rv = r[t] * rgc + rbc;
            if (rst && rselu) rv = selu_f(rv);
            f[q] = selu_f(x[t] * xgc + xbc + rv);
        }
        out[((long)b * C + c) * Tout + to] = fmaxf(f[0], f[1]);
    }
}

// ---------------- fused: out(bf16) = upsample2( selu( T(x) [+ res(bf16)] ) ) ----------------
template<int INBF>
__global__ __launch_bounds__(256) void up_fused_kernel(
    const void* __restrict__ x_, const float* __restrict__ xst,
    const float* __restrict__ xg, const float* __restrict__ xb, int xcpg,
    const unsigned short* __restrict__ res,
    unsigned short* __restrict__ out, int C, int Tin, long total)
{
    for (long idx = blockIdx.x * (long)blockDim.x + threadIdx.x; idx < total;
         idx += (long)gridDim.x * blockDim.x) {
        const int t = (int)(idx % Tin);
        const int c = (int)((idx / Tin) % C);
        const int b = (int)(idx / ((long)Tin * C));
        const float* s = &xst[2 * (b * NG_ + c / xcpg)];
        float v = INBF ? bf2f(((const unsigned short*)x_)[idx])
                       : ((const float*)x_)[idx];
        v = (v - s[0]) * s[1] * xg[c] + xb[c];
        if (res) v += bf2f(res[idx]);
        v = selu_f(v);
        unsigned short h = f2bf(v);
        unsigned pack = (unsigned)h | ((unsigned)h << 16);
        *(unsigned*)(out + (((long)b * C + c) * Tin + t) * 2) = pack;
    }
}

// ---------------- VQ ----------------
__global__ void wnorm_kernel(const float* __restrict__ codes, float* __restrict__ wn)
{
    int j = blockIdx.x * 256 + threadIdx.x;
    if (j >= VQN_) return;
    const float* c = codes + (long)j * VQD_;
    float s = 0.f;
#pragma unroll
    for (int i = 0; i < VQD_; ++i) s = fmaf(c[i], c[i], s);
    wn[j] = s;
}

// combine 4 per-slice argmin partials (ascending slice, strict < -> lowest-j ties)
__global__ void vq_combine_kernel(const float* __restrict__ vb, const int* __restrict__ vj,
                                  int* __restrict__ bjs, long stride, int NP)
{
    int n = blockIdx.x * 256 + threadIdx.x;
    if (n >= NP) return;
    float best = vb[n];
    int bj = vj[n];
#pragma unroll
    for (int s = 1; s < 4; ++s) {
        float v = vb[(long)s * stride + n];
        if (v < best) { best = v; bj = vj[(long)s * stride + n]; }
    }
    bjs[n] = bj;
}

// gather: write hq (f32, coalesced) + loss from f32 h
__global__ __launch_bounds__(256) void vq_gather_kernel(
    const float* __restrict__ h, const float* __restrict__ codes,
    const int* __restrict__ bjs, float* __restrict__ hq, float* __restrict__ loss,
    int T)
{
    const int n0 = blockIdx.x * 64;
    const int b  = n0 / T;
    const int tb = n0 % T;
    __shared__ int sbj[64];
    if (threadIdx.x < 64) sbj[threadIdx.x] = bjs[n0 + threadIdx.x];
    __syncthreads();

    float l = 0.f;
#pragma unroll
    for (int r = 0; r < (VQD_ * 64) / 256; ++r) {
        int idx = r * 256 + (int)threadIdx.x;
        int c  = idx >> 6, tl = idx & 63;
        float wv = codes[(long)sbj[tl] * VQD_ + c];
        long off = ((long)b * VQD_ + c) * T + tb + tl;
        hq[off] = wv;
        float df = h[off] - wv;
        l = fmaf(df, df, l);
    }
#pragma unroll
    for (int off = 32; off; off >>= 1) l += __shfl_down(l, off);
    if ((threadIdx.x & 63) == 0) atomicAdd(loss, l);
}

__global__ void zero_kernel(float* p) { p[0] = 0.f; }

__global__ void finalize_kernel(const float* __restrict__ loss, float* __restrict__ out,
                                float invNP, long off)
{
    float v = loss[0] * invNP;
    out[off]     = v;
    out[off + 1] = v;
}

// ---------------- host side ----------------
static inline int nblk(long total, int thr = 256, long cap = 262144) {
    long b = (total + thr - 1) / thr;
    if (b > cap) b = cap;
    if (b < 1) b = 1;
    return (int)b;
}
static inline int ldsz(int CI, int K, int TT = 64) {
    int span = TT + K - 1;
    int rs = (span + 3) & ~3;
    return CI * rs * 4;
}

struct WT {
    long w0, wxa, wxb, wxc, w2, wd2, wd0, total;
};
static WT wt_offsets() {
    WT o; long p = 0;
    o.w0   = p; p += (long)ORG_ * 7 * C1_;
    o.wxa  = p; p += (long)C1_ * 1 * (C1_ / 2);
    o.wxb  = p; p += 2L * 5 * (C1_ / 2);
    o.wxc  = p; p += (long)(C1_ / 2) * 1 * C1_;
    o.w2   = p; p += (long)C1_ * 3 * C2_;
    o.wd2  = p; p += (long)C2_ * 3 * C1_;
    o.wd0  = p; p += (long)C1_ * 7 * ORG_;
    o.total = p;
    return o;
}

static void run_chunk(const float* x, const float* const* W, const float* wt,
                      const WT& wo, const unsigned short* wbA, const unsigned short* wbB,
                      const float* wn, const float* wts, const float* neg2,
                      float* vbest4, int* vbj4, int* bjs, float* out,
                      float* A, float* Bb, float* Cc, float* st, float* lossbuf,
                      int Bc, long nbuf, hipStream_t stream)
{
    const float* g0_g  = W[1];
    const float* g0_b  = W[2];
    const float* gxa_g = W[4];
    const float* gxa_b = W[5];
    const float* gxb_g = W[7];
    const float* gxb_b = W[8];
    const float* gxc_g = W[10];
    const float* gxc_b = W[11];
    const float* bn2_g = W[13];
    const float* bn2_b = W[14];
    const float* embed = W[15];
    const float* gd2_g = W[17];
    const float* gd2_b = W[18];
    const float* gd1a_g= W[20];
    const float* gd1a_b= W[21];
    const float* gd1b_g= W[23];
    const float* gd1b_b= W[24];
    const float* bd0   = W[26];

    const int D_ = C1_ / 2;  // 64
    const int SLOT = 2048;
    float* st0 = st + 0 * SLOT;
    float* st1 = st + 1 * SLOT;
    float* st2 = st + 2 * SLOT;
    float* st3 = st + 3 * SLOT;
    float* st4 = st + 4 * SLOT;
    float* st5 = st + 5 * SLOT;
    float* st6 = st + 6 * SLOT;

    unsigned short* Au  = (unsigned short*)A;
    unsigned short* Bbu = (unsigned short*)Bb;
    unsigned short* Ccu = (unsigned short*)Cc;

    const int nbg = Bc * NG_;
    const int cpg1 = C1_ / NG_;

    int T = L_;  // 2048

    // ============ encoder (all f32, bit-stable for VQ argmin) ============
    conv_tile_kernel<7, 128, 512, 64, 1, 0><<<dim3(T / 64, Bc), 512, ldsz(ORG_, 7), stream>>>(
        x, wt + wo.w0, nullptr, nullptr, A, ORG_, T, ORG_, C1_,
        nullptr, nullptr, nullptr, 0, 0, nullptr, nullptr, nullptr, 0, 0);
    gn_stats_kernel<<<nbg, 256, 0, stream>>>(A, st0, C1_, T, NG_);

    conv_tile_kernel<1, 64, 512, 64, 2, 0><<<dim3(T / 64, Bc), 512, ldsz(C1_, 1), stream>>>(
        A, wt + wo.wxa, nullptr, nullptr, Bb, C1_, T, C1_, D_,
        st0, g0_g, g0_b, cpg1, 1, nullptr, nullptr, nullptr, 0, 0);
    gn_stats_kernel<<<nbg, 256, 0, stream>>>(Bb, st1, D_, T, NG_);

    conv_tile_kernel<5, 64, 512, 64, 1, 0><<<dim3(T / 64, Bc), 512, ldsz(D_, 5), stream>>>(
        Bb, wt + wo.wxb, nullptr, nullptr, Bb + nbuf / 2, D_, T, 2, 2,
        st1, gxa_g, gxa_b, D_ / NG_, 1, nullptr, nullptr, nullptr, 0, 0);
    gn_stats_kernel<<<nbg, 256, 0, stream>>>(Bb + nbuf / 2, st2, D_, T, NG_);

    conv_tile_kernel<1, 128, 512, 64, 2, 0><<<dim3(T / 64, Bc), 512, ldsz(D_, 1), stream>>>(
        Bb + nbuf / 2, wt + wo.wxc, nullptr, nullptr, Cc, D_, T, D_, C1_,
        st2, gxb_g, gxb_b, D_ / NG_, 1, nullptr, nullptr, nullptr, 0, 0);
    gn_stats_kernel<<<nbg, 256, 0, stream>>>(Cc, st3, C1_, T, NG_);

    {
        int Tout = T / 2;
        long tt = (long)Bc * C1_ * Tout;
        pool_fused_kernel<<<nblk(tt), 256, 0, stream>>>(
            Cc, st3, gxc_g, gxc_b, cpg1,
            A, st0, g0_g, g0_b, cpg1, 1,
            Bb, C1_, Tout, tt);
        T = Tout;
    }

    conv_tile_kernel<1, 64, 512, 64, 2, 0><<<dim3(T / 64, Bc), 512, ldsz(C1_, 1), stream>>>(
        Bb, wt + wo.wxa, nullptr, nullptr, Cc, C1_, T, C1_, D_,
        nullptr, nullptr, nullptr, 0, 0, nullptr, nullptr, nullptr, 0, 0);
    gn_stats_kernel<<<nbg, 256, 0, stream>>>(Cc, st1, D_, T, NG_);

    conv_tile_kernel<5, 64, 512, 64, 1, 0><<<dim3(T / 64, Bc), 512, ldsz(D_, 5), stream>>>(
        Cc, wt + wo.wxb, nullptr, nullptr, Cc + nbuf / 2, D_, T, 2, 2,
        st1, gxa_g, gxa_b, D_ / NG_, 1, nullptr, nullptr, nullptr, 0, 0);
    gn_stats_kernel<<<nbg, 256, 0, stream>>>(Cc + nbuf / 2, st2, D_, T, NG_);

    conv_tile_kernel<1, 128, 512, 64, 2, 0><<<dim3(T / 64, Bc), 512, ldsz(D_, 1), stream>>>(
        Cc + nbuf / 2, wt + wo.wxc, nullptr, nullptr, A, D_, T, D_, C1_,
        st2, gxb_g, gxb_b, D_ / NG_, 1, nullptr, nullptr, nullptr, 0, 0);
    gn_stats_kernel<<<nbg, 256, 0, stream>>>(A, st3, C1_, T, NG_);

    {
        int Tout = T / 2;
        long tt = (long)Bc * C1_ * Tout;
        pool_fused_kernel<<<nblk(tt), 256, 0, stream>>>(
            A, st3, gxc_g, gxc_b, cpg1,
            Bb, nullptr, nullptr, nullptr, 0, 0,
            Cc, C1_, Tout, tt);
        T = Tout;
    }

    conv_tile_kernel<3, 64, 512, 64, 1, 0><<<dim3(T / 64, Bc), 512, ldsz(C1_, 3), stream>>>(
        Cc, wt + wo.w2, bn2_g, bn2_b, Bb, C1_, T, C1_, C2_,
        nullptr, nullptr, nullptr, 0, 0, nullptr, nullptr, nullptr, 0, 0);

    // ============ VQ ============  (h in Bb -> hq in A)
    {
        int NP = Bc * T;
        conv_tile_kernel<1, 256, 512, 64, 8, 1><<<dim3(T / 64, Bc, 4), 512,
                                                  ldsz(VQD_, 1), stream>>>(
            Bb, wts, neg2, wn, nullptr,
            VQD_, T, VQD_, 256,
            nullptr, nullptr, nullptr, 0, 0, nullptr,
            vbest4, vbj4, 0, PTS_);
        vq_combine_kernel<<<(NP + 255) / 256, 256, 0, stream>>>(vbest4, vbj4, bjs, PTS_, NP);
        vq_gather_kernel<<<NP / 64, 256, 0, stream>>>(Bb, embed, bjs, A, lossbuf, T);
    }

    // ============ decoder (bf16 storage from up0 onward) ============
    conv_tile_kernel<3, 128, 512, 64, 1, 0><<<dim3(T / 64, Bc), 512, ldsz(C2_, 3), stream>>>(
        A, wt + wo.wd2, nullptr, nullptr, Bb, C2_, T, C2_, C1_,
        nullptr, nullptr, nullptr, 0, 0, nullptr, nullptr, nullptr, 0, 0);
    gn_stats_kernel<<<nbg, 256, 0, stream>>>(Bb, st4, C1_, T, NG_);

    {
        long tt = (long)Bc * C1_ * T;
        up_fused_kernel<0><<<nblk(tt), 256, 0, stream>>>(
            Bb, st4, gd2_g, gd2_b, cpg1, nullptr, Ccu, C1_, T, tt);
        T *= 2;
    }

    conv_mfma5_kernel<<<dim3(T / 64, Bc), 256, 0, stream>>>(
        Ccu, wbA, Au, T, nullptr, nullptr, nullptr, 0);
    gn_stats_bf16_kernel<<<nbg, 256, 0, stream>>>(Au, st5, C1_, T, NG_);

    conv_mfma5_kernel<<<dim3(T / 64, Bc), 256, 0, stream>>>(
        Au, wbB, Bbu, T, st5, gd1a_g, gd1a_b, cpg1);
    gn_stats_bf16_kernel<<<nbg, 256, 0, stream>>>(Bbu, st6, C1_, T, NG_);

    {
        long tt = (long)Bc * C1_ * T;
        up_fused_kernel<1><<<nblk(tt), 256, 0, stream>>>(
            Bbu, st6, gd1b_g, gd1b_b, cpg1, Ccu, Au, C1_, T, tt);
        T *= 2;
    }

    conv_mfma5_kernel<<<dim3(T / 64, Bc), 256, 0, stream>>>(
        Au, wbA, Ccu, T, nullptr, nullptr, nullptr, 0);
    gn_stats_bf16_kernel<<<nbg, 256, 0, stream>>>(Ccu, st5, C1_, T, NG_);

    conv_mfma5_kernel<<<dim3(T / 64, Bc), 256, 0, stream>>>(
        Ccu, wbB, Bbu, T, st5, gd1a_g, gd1a_b, cpg1);
    gn_stats_bf16_kernel<<<nbg, 256, 0, stream>>>(Bbu, st6, C1_, T, NG_);

    // deres0: 4-way ci-split into Cc partials (Ccu dead now), then combine
    {
        float* pbuf = Cc;
        conv_epi7_kernel<<<dim3(T / 256, Bc, 4), 256, 0, stream>>>(
            Bbu, wt + wo.wd0, pbuf, T, Bc,
            st6, gd1b_g, gd1b_b, cpg1, Au);
        long tt = (long)Bc * 4 * T;
        epi_comb_kernel<<<nblk(tt), 256, 0, stream>>>(pbuf, bd0, out, T, Bc, tt);
    }
}

extern "C" void kernel_launch(void* const* d_in, const int* in_sizes, int n_in,
                              void* d_out, int out_size, void* d_ws, size_t ws_size,
                              hipStream_t stream) {
    const float* x = (const float*)d_in[0];
    const float* W[27];
    for (int i = 0; i < 27; ++i) W[i] = (const float*)d_in[i + 1];

    float* out = (float*)d_out;
    const WT wo = wt_offsets();

    // ws: [wT f32 | mfma bf16 | wn | wts | neg2 | stats | loss | vbest4 | vbj4 | bjs | A | B | C]
    const long WT_F32  = 262144;
    const long WB_F32  = 2 * 81920 / 2;        // 81920
    const long WTS_F32 = VQN_ * VQD_;          // 65536
    const long ST_F32  = 8 * 2048;
    const long VQ_F32  = 4 * PTS_ + 4 * PTS_ + PTS_;   // vbest4 + vbj4 + bjs
    const long FIXED = WT_F32 + WB_F32 + 1024 + WTS_F32 + 256 + ST_F32 + 64 + VQ_F32;
    int Bc = 0;
    for (int cand = B_; cand >= 1; cand >>= 1) {
        size_t need = ((size_t)FIXED + (size_t)3 * cand * C1_ * L_) * sizeof(float);
        if (need <= ws_size) { Bc = cand; break; }
    }
    if (Bc == 0) return;

    float* wt            = (float*)d_ws;
    unsigned short* wbA  = (unsigned short*)(wt + WT_F32);
    unsigned short* wbB  = wbA + 81920;
    float* wn            = wt + WT_F32 + WB_F32;
    float* wts           = wn + 1024;
    float* neg2          = wts + WTS_F32;
    float* st            = neg2 + 256;
    float* lossbuf       = st + ST_F32;
    float* vbest4        = lossbuf + 64;
    int*   vbj4          = (int*)(vbest4 + 4 * PTS_);
    int*   bjs           = vbj4 + 4 * PTS_;
    const long nbuf = (long)Bc * C1_ * L_;
    float* A  = (float*)(bjs + PTS_);
    float* Bb = A + nbuf;
    float* Cc = Bb + nbuf;

    const int D_ = C1_ / 2;

    auto prep = [&](const float* w, long off, int CO, int cig, int K,
                    int so, int si, int sk, int koff) {
        int total = cig * K * CO;
        wprep_kernel<<<(total + 255) / 256, 256, 0, stream>>>(
            w, wt + off, CO, cig, K, so, si, sk, koff);
    };
    prep(W[0],  wo.w0,   C1_, ORG_, 7, ORG_ * 7, 7,        1,  0);
    prep(W[3],  wo.wxa,  D_,  C1_,  1, C1_,      1,        1,  0);
    prep(W[6],  wo.wxb,  D_,  2,    5, 2 * 5,    5,        1,  0);
    prep(W[9],  wo.wxc,  C1_, D_,   1, D_,       1,        1,  0);
    prep(W[12], wo.w2,   C2_, C1_,  3, C1_ * 3,  3,        1,  0);
    prep(W[16], wo.wd2,  C1_, C2_,  3, 3,        C1_ * 3, -1,  2);
    prep(W[25], wo.wd0,  ORG_, C1_, 7, 7,        ORG_ * 7, -1, 6);
    wprep_mfma_kernel<<<81920 / 256, 256, 0, stream>>>(W[19], wbA);  // wd1a
    wprep_mfma_kernel<<<81920 / 256, 256, 0, stream>>>(W[22], wbB);  // wd1b
    wnorm_kernel<<<(VQN_ + 255) / 256, 256, 0, stream>>>(W[15], wn);
    // scores weights: 4 slices of 256 codes, wts[i*256 + o] = embed[o*64 + i]
    for (int q = 0; q < 4; ++q) {
        wprep_kernel<<<(256 * VQD_ + 255) / 256, 256, 0, stream>>>(
            W[15] + (long)q * 256 * VQD_, wts + (long)q * 256 * VQD_,
            256, VQD_, 1, VQD_, 1, 1, 0);
    }
    fill_kernel<<<1, 256, 0, stream>>>(neg2, -2.f, 256);

    zero_kernel<<<1, 1, 0, stream>>>(lossbuf);

    for (int b0 = 0; b0 < B_; b0 += Bc) {
        const float* xc = x + (long)b0 * ORG_ * L_;
        float* outc = out + (long)b0 * ORG_ * L_;
        run_chunk(xc, W, wt, wo, wbA, wbB, wn, wts, neg2, vbest4, vbj4, bjs,
                  outc, A, Bb, Cc, st, lossbuf, Bc, nbuf, stream);
    }

    {
        float invNP = 1.f / (float)(B_ * (L_ / 4));  // N = 65536
        finalize_kernel<<<1, 1, 0, stream>>>(lossbuf, out, invNP, (long)out_size - 2);
    }
}

// Round 18
// 1972.057 us; speedup vs baseline: 1.0252x; 1.0252x over previous
//
#include <hip/hip_runtime.h>
#include <math.h>

// ---------------- constants ----------------
static constexpr int B_   = 128;
static constexpr int ORG_ = 4;
static constexpr int L_   = 2048;
static constexpr int C1_  = 128;
static constexpr int C2_  = 64;
static constexpr int NG_  = 8;
static constexpr int VQD_ = 64;
static constexpr int VQN_ = 1024;
static constexpr long PTS_ = (long)B_ * (L_ / 4);   // 65536 max points

typedef __attribute__((ext_vector_type(8))) short bf16x8;
typedef __attribute__((ext_vector_type(4))) float f32x4;

__device__ __forceinline__ float selu_f(float x) {
    const float scale = 1.0507009873554805f;
    const float alpha = 1.6732632423543772f;
    return scale * (x > 0.f ? x : alpha * expm1f(x));
}
__device__ __forceinline__ unsigned short f2bf(float x) {
    unsigned u = __float_as_uint(x);
    u = (u + 0x7FFFu + ((u >> 16) & 1u)) >> 16;
    return (unsigned short)u;
}
__device__ __forceinline__ float bf2f(unsigned short u) {
    return __uint_as_float((unsigned)u << 16);
}

// ---------------- weight prep (f32 direct-conv layout) ----------------
__global__ void wprep_kernel(const float* __restrict__ w, float* __restrict__ wT,
                             int CO, int cig, int K, int so, int si, int sk, int koff)
{
    int idx = blockIdx.x * 256 + threadIdx.x;
    int total = cig * K * CO;
    if (idx >= total) return;
    int o = idx % CO;
    int r = idx / CO;
    int i = r / K, k = r % K;
    wT[idx] = w[(long)o * so + (long)i * si + (long)k * sk + koff];
}

// ---------------- weight prep (MFMA bf16 layout) for tconv 128x128 K=5 ----------------
__global__ void wprep_mfma_kernel(const float* __restrict__ w, unsigned short* __restrict__ wb)
{
    int idx = blockIdx.x * 256 + threadIdx.x;   // total 81920
    if (idx >= 5 * 16 * 128 * 8) return;
    int j  = idx & 7;
    int o  = (idx >> 3) & 127;
    int kk = idx >> 10;          // 0..79
    int ig = kk & 3, ic = (kk >> 2) & 3, k = kk >> 4;
    int i  = ic * 32 + ig * 8 + j;
    wb[idx] = f2bf(w[(long)i * (128 * 5) + o * 5 + (4 - k)]);
}

__global__ void fill_kernel(float* p, float v, int n)
{
    int i = blockIdx.x * 256 + threadIdx.x;
    if (i < n) p[i] = v;
}

__global__ void zero_n_kernel(float* p, int n)
{
    int i = blockIdx.x * 256 + threadIdx.x;
    if (i < n) p[i] = 0.f;
}

// raw (s,ss) -> (mu, rsig)
__global__ void gnfin_kernel(const float* __restrict__ raw, float* __restrict__ st,
                             float invn, int n)
{
    int i = blockIdx.x * 64 + threadIdx.x;
    if (i >= n) return;
    float s = raw[2 * i], ss = raw[2 * i + 1];
    float mu = s * invn;
    float var = ss * invn - mu * mu;
    st[2 * i] = mu;
    st[2 * i + 1] = rsqrtf(var + 1e-5f);
}

// ---------------- LDS-tiled f32 conv with optional fused input transform ----------------
// VQ=1: per-slot argmin of score=fma(acc,scale,bias) -> vbest/vbj; blockIdx.z selects the
//       256-code slice (weights/bias/jbase/outputs offset by z).
template<int K, int CO, int NTHR, int TT, int OT, int VQ>
__global__ __launch_bounds__(NTHR) void conv_tile_kernel(
    const float* __restrict__ in, const float* __restrict__ wT,
    const float* __restrict__ scale, const float* __restrict__ bias,
    float* __restrict__ out,
    int CI, int T, int cig, int cog,
    const float* __restrict__ ist, const float* __restrict__ ig,
    const float* __restrict__ ibt, int icpg, int iselu,
    const float* __restrict__ res,
    float* __restrict__ vbest, int* __restrict__ vbj, int jbase, long vstride)
{
    constexpr int P    = (K - 1) / 2;
    constexpr int SPAN = TT + K - 1;
    constexpr int RS   = (SPAN + 3) & ~3;
    constexpr int NO   = CO / OT;
    constexpr int NT   = (CO * TT) / (NTHR * OT);
    constexpr int XW   = NT + K - 1;
    extern __shared__ float lds[];

    if constexpr (VQ) {
        const int z = blockIdx.z;
        wT    += (long)z * cig * K * CO;
        bias  += (long)z * CO;
        vbest += (long)z * vstride;
        vbj   += (long)z * vstride;
        jbase += z * CO;
    }

    const int tile = blockIdx.x;
    const int b    = blockIdx.y;
    const int t0g  = tile * TT;
    const float* inb = in + (long)b * CI * T;

    for (int idx = threadIdx.x; idx < CI * SPAN; idx += NTHR) {
        int c = idx / SPAN, j = idx % SPAN;
        int tt = t0g + j - P;
        float v = 0.f;
        if (tt >= 0 && tt < T) {
            v = inb[(long)c * T + tt];
            if (ist) {
                const float* s = &ist[2 * (b * NG_ + c / icpg)];
                v = (v - s[0]) * s[1] * ig[c] + ibt[c];
                if (res) v += res[((long)b * CI + c) * T + tt];
                if (iselu) v = selu_f(v);
            }
        }
        lds[c * RS + j] = v;
    }
    __syncthreads();

    const int o0   = (threadIdx.x % NO) * OT;
    const int slot = threadIdx.x / NO;
    const int t0   = slot * NT;
    const int g    = o0 / cog;
    const float* wrow = wT + o0;

    float acc[OT][NT];
#pragma unroll
    for (int oo = 0; oo < OT; ++oo)
#pragma unroll
        for (int u = 0; u < NT; ++u) acc[oo][u] = 0.f;

#pragma unroll 4
    for (int i = 0; i < cig; ++i) {
        const int irow = g * cig + i;
        float xin[(XW + 3) & ~3];
        if constexpr (NT % 4 == 0) {
            constexpr int X4 = (XW + 3) / 4;
            const float4* l4 = reinterpret_cast<const float4*>(&lds[irow * RS + t0]);
#pragma unroll
            for (int j = 0; j < X4; ++j) {
                float4 v = l4[j];
                xin[4 * j]     = v.x;
                xin[4 * j + 1] = v.y;
                xin[4 * j + 2] = v.z;
                xin[4 * j + 3] = v.w;
            }
        } else {
#pragma unroll
            for (int j = 0; j < XW; ++j) xin[j] = lds[irow * RS + t0 + j];
        }
        float wk[OT][K];
#pragma unroll
        for (int oo = 0; oo < OT; ++oo)
#pragma unroll
            for (int k = 0; k < K; ++k) wk[oo][k] = wrow[(i * K + k) * CO + oo];
#pragma unroll
        for (int oo = 0; oo < OT; ++oo)
#pragma unroll
            for (int u = 0; u < NT; ++u)
#pragma unroll
                for (int k = 0; k < K; ++k)
                    acc[oo][u] = fmaf(xin[u + k], wk[oo][k], acc[oo][u]);
    }

    if constexpr (VQ) {
        constexpr int RW = (NO >= 64) ? 64 : 32;   // reduce width: one t-slot per RW lanes
        const int lane = threadIdx.x & 63;
#pragma unroll
        for (int u = 0; u < NT; ++u) {
            float bv = 3.4e38f;
            int bj = 0;
#pragma unroll
            for (int oo = 0; oo < OT; ++oo) {
                const int o = o0 + oo;
                float sv = fmaf(acc[oo][u], scale[o], bias[o]);
                if (sv < bv) { bv = sv; bj = jbase + o; }
            }
#pragma unroll
            for (int off = 1; off < RW; off <<= 1) {
                float v2 = __shfl_xor(bv, off);
                int   j2 = __shfl_xor(bj, off);
                if (v2 < bv || (v2 == bv && j2 < bj)) { bv = v2; bj = j2; }
            }
            if ((lane & (RW - 1)) == 0) {
                long n = (long)b * T + t0g + t0 + u;
                vbest[n] = bv;
                vbj[n]   = bj;
            }
        }
    } else {
#pragma unroll
        for (int oo = 0; oo < OT; ++oo) {
            const int o = o0 + oo;
            const float sc = scale ? scale[o] : 1.f;
            const float bi = bias  ? bias[o]  : 0.f;
            float* ob = out + ((long)b * CO + o) * T + t0g + t0;
#pragma unroll
            for (int u = 0; u < NT; ++u) ob[u] = acc[oo][u] * sc + bi;
        }
    }
}

// ---------------- deres0 epilogue conv, ci-split: bf16 in/res, f32 partials ----------------
// NOTE: the cc-loop must NOT be unrolled/pipelined — the wave-private row[] window is
// cross-lane wave-synchronous (write-then-read each iteration, no barrier). r16 regression.
__global__ __launch_bounds__(256) void conv_epi7_kernel(
    const unsigned short* __restrict__ in, const float* __restrict__ wT,
    float* __restrict__ pbuf, int T, int Bc,
    const float* __restrict__ ist, const float* __restrict__ ig_,
    const float* __restrict__ ibt, int icpg,
    const unsigned short* __restrict__ res)
{
    __shared__ float wlds[32 * 7 * 4];
    __shared__ float rows[4][80];

    const int z   = blockIdx.z;
    const int ci0 = z * 32;

    for (int idx = threadIdx.x; idx < 32 * 7 * 4; idx += 256)
        wlds[idx] = wT[ci0 * 7 * 4 + idx];
    __syncthreads();

    const int wid  = threadIdx.x >> 6;
    const int lane = threadIdx.x & 63;
    const int b    = blockIdx.y;
    const int t0w  = blockIdx.x * 256 + wid * 64;
    const int t    = t0w + lane;
    float* row = rows[wid];
    const long base = (long)b * 128 * T;

    float acc0 = 0.f, acc1 = 0.f, acc2 = 0.f, acc3 = 0.f;

    for (int cc = 0; cc < 32; ++cc) {
        const int ci = ci0 + cc;
        const float* s = &ist[2 * (b * NG_ + ci / icpg)];
        const float mu = s[0], rs = s[1];
        const float gc = ig_[ci], bc = ibt[ci];
        const long cbase = base + (long)ci * T;

        float v = bf2f(in[cbase + t]);
        v = (v - mu) * rs * gc + bc;
        v += bf2f(res[cbase + t]);
        v = selu_f(v);
        row[3 + lane] = v;

        if (lane < 3 || lane >= 61) {
            int th   = (lane < 3) ? (t0w - 3 + lane) : (t0w + 3 + lane);
            int ridx = (lane < 3) ? lane : (lane + 6);
            float h = 0.f;
            if (th >= 0 && th < T) {
                h = bf2f(in[cbase + th]);
                h = (h - mu) * rs * gc + bc;
                h += bf2f(res[cbase + th]);
                h = selu_f(h);
            }
            row[ridx] = h;
        }

        float xin[7];
#pragma unroll
        for (int j = 0; j < 7; ++j) xin[j] = row[lane + j];
#pragma unroll
        for (int k = 0; k < 7; ++k) {
            float4 w4 = *(const float4*)&wlds[(cc * 7 + k) * 4];
            acc0 = fmaf(xin[k], w4.x, acc0);
            acc1 = fmaf(xin[k], w4.y, acc1);
            acc2 = fmaf(xin[k], w4.z, acc2);
            acc3 = fmaf(xin[k], w4.w, acc3);
        }
    }

    const long half = (long)Bc * 4 * T;
    float* pb = pbuf + (long)z * half + ((long)b * 4) * T + t;
    pb[0 * T] = acc0;
    pb[1 * T] = acc1;
    pb[2 * T] = acc2;
    pb[3 * T] = acc3;
}

// combine 4 ci-partials + bias -> out
__global__ void epi_comb_kernel(const float* __restrict__ pbuf,
                                const float* __restrict__ bias,
                                float* __restrict__ out, int T, int Bc, long total)
{
    const long half = (long)Bc * 4 * T;
    for (long idx = blockIdx.x * (long)blockDim.x + threadIdx.x; idx < total;
         idx += (long)gridDim.x * blockDim.x) {
        const int o = (int)((idx / T) & 3);
        float v = ((pbuf[idx] + pbuf[half + idx]) + pbuf[2 * half + idx])
                  + pbuf[3 * half + idx];
        out[idx] = v + bias[o];
    }
}

// ---------------- MFMA bf16 conv v4: bf16 in, bf16 out, optional fused GN raw stats ----
// Block 256 thr / 4 waves; tile 64t x 128o (18.5 KB LDS).
// Wave partition by OUTPUT CHANNEL: wave w owns ot in {2w, 2w+1} (group == ot, cpg=16),
// so stats per oo are a thread-local 16-value sum + one full-wave reduce + 2 atomics.
__global__ __launch_bounds__(256) void conv_mfma5_kernel(
    const unsigned short* __restrict__ in, const unsigned short* __restrict__ wb,
    unsigned short* __restrict__ out, int T,
    const float* __restrict__ ist, const float* __restrict__ ig_,
    const float* __restrict__ ibt, int icpg,
    float* __restrict__ ostat)
{
    constexpr int SPAN = 68, RSI = 136;
    __shared__ unsigned short xlds[SPAN * RSI];   // 18.5 KB

    const int t0g = blockIdx.x * 64;
    const int b   = blockIdx.y;
    const unsigned short* inb = in + (long)b * 128 * T;

    for (int idx = threadIdx.x; idx < 128 * SPAN; idx += 256) {
        int i = idx / SPAN, j = idx % SPAN;
        int tt = t0g + j - 2;
        unsigned short raw = 0;
        if (tt >= 0 && tt < T) {
            raw = inb[(long)i * T + tt];
            if (ist) {
                const float* s = &ist[2 * (b * NG_ + i / icpg)];
                float v = selu_f((bf2f(raw) - s[0]) * s[1] * ig_[i] + ibt[i]);
                raw = f2bf(v);
            }
        }
        xlds[j * RSI + i] = raw;
    }
    __syncthreads();

    const int lane = threadIdx.x & 63;
    const int wid  = threadIdx.x >> 6;   // wave owns ot = {2*wid, 2*wid+1}
    const int mr   = lane & 15;
    const int kg   = lane >> 4;

    f32x4 acc[4][2];
#pragma unroll
    for (int m = 0; m < 4; ++m)
#pragma unroll
        for (int oo = 0; oo < 2; ++oo) acc[m][oo] = (f32x4){0.f, 0.f, 0.f, 0.f};

#pragma unroll
    for (int k = 0; k < 5; ++k) {
#pragma unroll
        for (int ic = 0; ic < 4; ++ic) {
            bf16x8 a[4];
#pragma unroll
            for (int m = 0; m < 4; ++m)
                a[m] = *(const bf16x8*)&xlds[(m * 16 + mr + k) * RSI + ic * 32 + kg * 8];
            const unsigned short* wp = wb + (((k * 16 + ic * 4 + kg) * 128) + mr) * 8;
#pragma unroll
            for (int oo = 0; oo < 2; ++oo) {
                const int ot = wid * 2 + oo;
                bf16x8 bfr = *(const bf16x8*)(wp + ot * 16 * 8);
#pragma unroll
                for (int m = 0; m < 4; ++m)
                    acc[m][oo] = __builtin_amdgcn_mfma_f32_16x16x32_bf16(a[m], bfr, acc[m][oo], 0, 0, 0);
            }
        }
    }

#pragma unroll
    for (int m = 0; m < 4; ++m) {
#pragma unroll
        for (int oo = 0; oo < 2; ++oo) {
            const int ot = wid * 2 + oo;
            int o = ot * 16 + mr;
            ushort4 v;
            v.x = f2bf(acc[m][oo][0]);
            v.y = f2bf(acc[m][oo][1]);
            v.z = f2bf(acc[m][oo][2]);
            v.w = f2bf(acc[m][oo][3]);
            *(ushort4*)&out[((long)b * 128 + o) * T + t0g + m * 16 + kg * 4] = v;
        }
    }

    // fused GN raw stats (decoder-only; last-ulp tolerance)
    if (ostat) {
#pragma unroll
        for (int oo = 0; oo < 2; ++oo) {
            float s = 0.f, ss = 0.f;
#pragma unroll
            for (int m = 0; m < 4; ++m)
#pragma unroll
                for (int q = 0; q < 4; ++q) {
                    float v = acc[m][oo][q];
                    s += v; ss = fmaf(v, v, ss);
                }
#pragma unroll
            for (int off = 32; off; off >>= 1) {
                s  += __shfl_down(s, off);
                ss += __shfl_down(ss, off);
            }
            if (lane == 0) {
                const int grp = wid * 2 + oo;
                atomicAdd(&ostat[2 * (b * NG_ + grp)],     s);
                atomicAdd(&ostat[2 * (b * NG_ + grp) + 1], ss);
            }
        }
    }
}

// ---------------- GroupNorm stats (f32, encoder) ----------------
__global__ __launch_bounds__(256) void gn_stats_kernel(
    const float* __restrict__ x, float* __restrict__ stats,
    int C, int T, int G)
{
    const int bg = blockIdx.x;
    const int cpg = C / G;
    const int b = bg / G, g = bg % G;
    const float* base = x + ((long)b * C + (long)g * cpg) * T;
    const long n4 = (long)cpg * T / 4;
    const float4* b4 = (const float4*)base;
    float s = 0.f, ss = 0.f;
    for (long i = threadIdx.x; i < n4; i += blockDim.x) {
        float4 v = b4[i];
        s += v.x + v.y + v.z + v.w;
        ss += v.x * v.x + v.y * v.y + v.z * v.z + v.w * v.w;
    }
#pragma unroll
    for (int off = 32; off; off >>= 1) {
        s  += __shfl_down(s, off);
        ss += __shfl_down(ss, off);
    }
    __shared__ float sh_s[4], sh_ss[4];
    const int wid = threadIdx.x >> 6, lane = threadIdx.x & 63;
    if (lane == 0) { sh_s[wid] = s; sh_ss[wid] = ss; }
    __syncthreads();
    if (threadIdx.x == 0) {
        float S = 0.f, SS = 0.f;
        for (int i = 0; i < 4; ++i) { S += sh_s[i]; SS += sh_ss[i]; }
        float inv_n = 1.f / (float)((long)cpg * T);
        float mu  = S * inv_n;
        float var = SS * inv_n - mu * mu;
        stats[2 * bg]     = mu;
        stats[2 * bg + 1] = rsqrtf(var + 1e-5f);
    }
}

// ---------------- fused: out = maxpool2( selu( T1(x) + T2(r) ) ) (f32, encoder) ----------------
__global__ __launch_bounds__(256) void pool_fused_kernel(
    const float* __restrict__ x, const float* __restrict__ xst,
    const float* __restrict__ xg, const float* __restrict__ xb, int xcpg,
    const float* __restrict__ r, const float* __restrict__ rst,
    const float* __restrict__ rg, const float* __restrict__ rb, int rcpg, int rselu,
    float* __restrict__ out, int C, int Tout, long total)
{
    for (long idx = blockIdx.x * (long)blockDim.x + threadIdx.x; idx < total;
         idx += (long)gridDim.x * blockDim.x) {
        const int to = (int)(idx % Tout);
        const int c  = (int)((idx / Tout) % C);
        const int b  = (int)(idx / ((long)Tout * C));
        const long base = ((long)b * C + c) * (2 * Tout);
        const float* sx = &xst[2 * (b * NG_ + c / xcpg)];
        const float xgc = sx[1] * xg[c], xbc = xb[c] - sx[0] * sx[1] * xg[c];
        float rgc = 1.f, rbc = 0.f;
        if (rst) {
            const float* sr = &rst[2 * (b * NG_ + c / rcpg)];
            rgc = sr[1] * rg[c]; rbc = rb[c] - sr[0] * sr[1] * rg[c];
        }
        float f[2];
#pragma unroll
        for (int q = 0; q < 2; ++q) {
            long t = base + 2 * to + q;
            float rv = r[t] * rgc + rbc;
            if (rst && rselu) rv = selu_f(rv);
            f[q] = selu_f(x[t] * xgc + xbc + rv);
        }
        out[((long)b * C + c) * Tout + to] = fmaxf(f[0], f[1]);
    }
}

// ---------------- fused: out(bf16) = upsample2( selu( T(x) [+ res(bf16)] ) ) ----------------
template<int INBF>
__global__ __launch_bounds__(256) void up_fused_kernel(
    const void* __restrict__ x_, const float* __restrict__ xst,
    const float* __restrict__ xg, const float* __restrict__ xb, int xcpg,
    const unsigned short* __restrict__ res,
    unsigned short* __restrict__ out, int C, int Tin, long total)
{
    for (long idx = blockIdx.x * (long)blockDim.x + threadIdx.x; idx < total;
         idx += (long)gridDim.x * blockDim.x) {
        const int t = (int)(idx % Tin);
        const int c = (int)((idx / Tin) % C);
        const int b = (int)(idx / ((long)Tin * C));
        const float* s = &xst[2 * (b * NG_ + c / xcpg)];
        float v = INBF ? bf2f(((const unsigned short*)x_)[idx])
                       : ((const float*)x_)[idx];
        v = (v - s[0]) * s[1] * xg[c] + xb[c];
        if (res) v += bf2f(res[idx]);
        v = selu_f(v);
        unsigned short h = f2bf(v);
        unsigned pack = (unsigned)h | ((unsigned)h << 16);
        *(unsigned*)(out + (((long)b * C + c) * Tin + t) * 2) = pack;
    }
}

// ---------------- VQ ----------------
__global__ void wnorm_kernel(const float* __restrict__ codes, float* __restrict__ wn)
{
    int j = blockIdx.x * 256 + threadIdx.x;
    if (j >= VQN_) return;
    const float* c = codes + (long)j * VQD_;
    float s = 0.f;
#pragma unroll
    for (int i = 0; i < VQD_; ++i) s = fmaf(c[i], c[i], s);
    wn[j] = s;
}

// combine 4 per-slice argmin partials (ascending slice, strict < -> lowest-j ties)
__global__ void vq_combine_kernel(const float* __restrict__ vb, const int* __restrict__ vj,
                                  int* __restrict__ bjs, long stride, int NP)
{
    int n = blockIdx.x * 256 + threadIdx.x;
    if (n >= NP) return;
    float best = vb[n];
    int bj = vj[n];
#pragma unroll
    for (int s = 1; s < 4; ++s) {
        float v = vb[(long)s * stride + n];
        if (v < best) { best = v; bj = vj[(long)s * stride + n]; }
    }
    bjs[n] = bj;
}

// gather: write hq (f32, coalesced) + loss from f32 h
__global__ __launch_bounds__(256) void vq_gather_kernel(
    const float* __restrict__ h, const float* __restrict__ codes,
    const int* __restrict__ bjs, float* __restrict__ hq, float* __restrict__ loss,
    int T)
{
    const int n0 = blockIdx.x * 64;
    const int b  = n0 / T;
    const int tb = n0 % T;
    __shared__ int sbj[64];
    if (threadIdx.x < 64) sbj[threadIdx.x] = bjs[n0 + threadIdx.x];
    __syncthreads();

    float l = 0.f;
#pragma unroll
    for (int r = 0; r < (VQD_ * 64) / 256; ++r) {
        int idx = r * 256 + (int)threadIdx.x;
        int c  = idx >> 6, tl = idx & 63;
        float wv = codes[(long)sbj[tl] * VQD_ + c];
        long off = ((long)b * VQD_ + c) * T + tb + tl;
        hq[off] = wv;
        float df = h[off] - wv;
        l = fmaf(df, df, l);
    }
#pragma unroll
    for (int off = 32; off; off >>= 1) l += __shfl_down(l, off);
    if ((threadIdx.x & 63) == 0) atomicAdd(loss, l);
}

__global__ void zero_kernel(float* p) { p[0] = 0.f; }

__global__ void finalize_kernel(const float* __restrict__ loss, float* __restrict__ out,
                                float invNP, long off)
{
    float v = loss[0] * invNP;
    out[off]     = v;
    out[off + 1] = v;
}

// ---------------- host side ----------------
static inline int nblk(long total, int thr = 256, long cap = 262144) {
    long b = (total + thr - 1) / thr;
    if (b > cap) b = cap;
    if (b < 1) b = 1;
    return (int)b;
}
static inline int ldsz(int CI, int K, int TT = 64) {
    int span = TT + K - 1;
    int rs = (span + 3) & ~3;
    return CI * rs * 4;
}

struct WT {
    long w0, wxa, wxb, wxc, w2, wd2, wd0, total;
};
static WT wt_offsets() {
    WT o; long p = 0;
    o.w0   = p; p += (long)ORG_ * 7 * C1_;
    o.wxa  = p; p += (long)C1_ * 1 * (C1_ / 2);
    o.wxb  = p; p += 2L * 5 * (C1_ / 2);
    o.wxc  = p; p += (long)(C1_ / 2) * 1 * C1_;
    o.w2   = p; p += (long)C1_ * 3 * C2_;
    o.wd2  = p; p += (long)C2_ * 3 * C1_;
    o.wd0  = p; p += (long)C1_ * 7 * ORG_;
    o.total = p;
    return o;
}

static void run_chunk(const float* x, const float* const* W, const float* wt,
                      const WT& wo, const unsigned short* wbA, const unsigned short* wbB,
                      const float* wn, const float* wts, const float* neg2,
                      float* vbest4, int* vbj4, int* bjs, float* out,
                      float* A, float* Bb, float* Cc, float* st, float* lossbuf,
                      int Bc, long nbuf, hipStream_t stream)
{
    const float* g0_g  = W[1];
    const float* g0_b  = W[2];
    const float* gxa_g = W[4];
    const float* gxa_b = W[5];
    const float* gxb_g = W[7];
    const float* gxb_b = W[8];
    const float* gxc_g = W[10];
    const float* gxc_b = W[11];
    const float* bn2_g = W[13];
    const float* bn2_b = W[14];
    const float* embed = W[15];
    const float* gd2_g = W[17];
    const float* gd2_b = W[18];
    const float* gd1a_g= W[20];
    const float* gd1a_b= W[21];
    const float* gd1b_g= W[23];
    const float* gd1b_b= W[24];
    const float* bd0   = W[26];

    const int D_ = C1_ / 2;  // 64
    const int SLOT = 2048;
    float* st0 = st + 0 * SLOT;
    float* st1 = st + 1 * SLOT;
    float* st2 = st + 2 * SLOT;
    float* st3 = st + 3 * SLOT;
    float* st4 = st + 4 * SLOT;
    float* st5 = st + 5 * SLOT;
    float* st6 = st + 6 * SLOT;
    float* stR = st + 8 * SLOT;   // 4 raw decoder-stat slots

    unsigned short* Au  = (unsigned short*)A;
    unsigned short* Bbu = (unsigned short*)Bb;
    unsigned short* Ccu = (unsigned short*)Cc;

    const int nbg = Bc * NG_;
    const int cpg1 = C1_ / NG_;

    int T = L_;  // 2048

    // zero raw decoder-stat slots for this chunk
    zero_n_kernel<<<(4 * SLOT + 255) / 256, 256, 0, stream>>>(stR, 4 * SLOT);

    // ============ encoder (all f32, bit-stable for VQ argmin) ============
    conv_tile_kernel<7, 128, 512, 64, 1, 0><<<dim3(T / 64, Bc), 512, ldsz(ORG_, 7), stream>>>(
        x, wt + wo.w0, nullptr, nullptr, A, ORG_, T, ORG_, C1_,
        nullptr, nullptr, nullptr, 0, 0, nullptr, nullptr, nullptr, 0, 0);
    gn_stats_kernel<<<nbg, 256, 0, stream>>>(A, st0, C1_, T, NG_);

    conv_tile_kernel<1, 64, 512, 64, 2, 0><<<dim3(T / 64, Bc), 512, ldsz(C1_, 1), stream>>>(
        A, wt + wo.wxa, nullptr, nullptr, Bb, C1_, T, C1_, D_,
        st0, g0_g, g0_b, cpg1, 1, nullptr, nullptr, nullptr, 0, 0);
    gn_stats_kernel<<<nbg, 256, 0, stream>>>(Bb, st1, D_, T, NG_);

    conv_tile_kernel<5, 64, 512, 64, 1, 0><<<dim3(T / 64, Bc), 512, ldsz(D_, 5), stream>>>(
        Bb, wt + wo.wxb, nullptr, nullptr, Bb + nbuf / 2, D_, T, 2, 2,
        st1, gxa_g, gxa_b, D_ / NG_, 1, nullptr, nullptr, nullptr, 0, 0);
    gn_stats_kernel<<<nbg, 256, 0, stream>>>(Bb + nbuf / 2, st2, D_, T, NG_);

    conv_tile_kernel<1, 128, 512, 64, 2, 0><<<dim3(T / 64, Bc), 512, ldsz(D_, 1), stream>>>(
        Bb + nbuf / 2, wt + wo.wxc, nullptr, nullptr, Cc, D_, T, D_, C1_,
        st2, gxb_g, gxb_b, D_ / NG_, 1, nullptr, nullptr, nullptr, 0, 0);
    gn_stats_kernel<<<nbg, 256, 0, stream>>>(Cc, st3, C1_, T, NG_);

    {
        int Tout = T / 2;
        long tt = (long)Bc * C1_ * Tout;
        pool_fused_kernel<<<nblk(tt), 256, 0, stream>>>(
            Cc, st3, gxc_g, gxc_b, cpg1,
            A, st0, g0_g, g0_b, cpg1, 1,
            Bb, C1_, Tout, tt);
        T = Tout;
    }

    conv_tile_kernel<1, 64, 512, 64, 2, 0><<<dim3(T / 64, Bc), 512, ldsz(C1_, 1), stream>>>(
        Bb, wt + wo.wxa, nullptr, nullptr, Cc, C1_, T, C1_, D_,
        nullptr, nullptr, nullptr, 0, 0, nullptr, nullptr, nullptr, 0, 0);
    gn_stats_kernel<<<nbg, 256, 0, stream>>>(Cc, st1, D_, T, NG_);

    conv_tile_kernel<5, 64, 512, 64, 1, 0><<<dim3(T / 64, Bc), 512, ldsz(D_, 5), stream>>>(
        Cc, wt + wo.wxb, nullptr, nullptr, Cc + nbuf / 2, D_, T, 2, 2,
        st1, gxa_g, gxa_b, D_ / NG_, 1, nullptr, nullptr, nullptr, 0, 0);
    gn_stats_kernel<<<nbg, 256, 0, stream>>>(Cc + nbuf / 2, st2, D_, T, NG_);

    conv_tile_kernel<1, 128, 512, 64, 2, 0><<<dim3(T / 64, Bc), 512, ldsz(D_, 1), stream>>>(
        Cc + nbuf / 2, wt + wo.wxc, nullptr, nullptr, A, D_, T, D_, C1_,
        st2, gxb_g, gxb_b, D_ / NG_, 1, nullptr, nullptr, nullptr, 0, 0);
    gn_stats_kernel<<<nbg, 256, 0, stream>>>(A, st3, C1_, T, NG_);

    {
        int Tout = T / 2;
        long tt = (long)Bc * C1_ * Tout;
        pool_fused_kernel<<<nblk(tt), 256, 0, stream>>>(
            A, st3, gxc_g, gxc_b, cpg1,
            Bb, nullptr, nullptr, nullptr, 0, 0,
            Cc, C1_, Tout, tt);
        T = Tout;
    }

    conv_tile_kernel<3, 64, 512, 64, 1, 0><<<dim3(T / 64, Bc), 512, ldsz(C1_, 3), stream>>>(
        Cc, wt + wo.w2, bn2_g, bn2_b, Bb, C1_, T, C1_, C2_,
        nullptr, nullptr, nullptr, 0, 0, nullptr, nullptr, nullptr, 0, 0);

    // ============ VQ ============  (h in Bb -> hq in A)
    {
        int NP = Bc * T;
        conv_tile_kernel<1, 256, 512, 64, 8, 1><<<dim3(T / 64, Bc, 4), 512,
                                                  ldsz(VQD_, 1), stream>>>(
            Bb, wts, neg2, wn, nullptr,
            VQD_, T, VQD_, 256,
            nullptr, nullptr, nullptr, 0, 0, nullptr,
            vbest4, vbj4, 0, PTS_);
        vq_combine_kernel<<<(NP + 255) / 256, 256, 0, stream>>>(vbest4, vbj4, bjs, PTS_, NP);
        vq_gather_kernel<<<NP / 64, 256, 0, stream>>>(Bb, embed, bjs, A, lossbuf, T);
    }

    // ============ decoder (bf16 storage from up0 onward) ============
    conv_tile_kernel<3, 128, 512, 64, 1, 0><<<dim3(T / 64, Bc), 512, ldsz(C2_, 3), stream>>>(
        A, wt + wo.wd2, nullptr, nullptr, Bb, C2_, T, C2_, C1_,
        nullptr, nullptr, nullptr, 0, 0, nullptr, nullptr, nullptr, 0, 0);
    gn_stats_kernel<<<nbg, 256, 0, stream>>>(Bb, st4, C1_, T, NG_);

    {
        long tt = (long)Bc * C1_ * T;
        up_fused_kernel<0><<<nblk(tt), 256, 0, stream>>>(
            Bb, st4, gd2_g, gd2_b, cpg1, nullptr, Ccu, C1_, T, tt);
        T *= 2;
    }

    conv_mfma5_kernel<<<dim3(T / 64, Bc), 256, 0, stream>>>(
        Ccu, wbA, Au, T, nullptr, nullptr, nullptr, 0, stR + 0 * SLOT);
    gnfin_kernel<<<(nbg + 63) / 64, 64, 0, stream>>>(stR + 0 * SLOT, st5, 1.f / (16.f * T), nbg);

    conv_mfma5_kernel<<<dim3(T / 64, Bc), 256, 0, stream>>>(
        Au, wbB, Bbu, T, st5, gd1a_g, gd1a_b, cpg1, stR + 1 * SLOT);
    gnfin_kernel<<<(nbg + 63) / 64, 64, 0, stream>>>(stR + 1 * SLOT, st6, 1.f / (16.f * T), nbg);

    {
        long tt = (long)Bc * C1_ * T;
        up_fused_kernel<1><<<nblk(tt), 256, 0, stream>>>(
            Bbu, st6, gd1b_g, gd1b_b, cpg1, Ccu, Au, C1_, T, tt);
        T *= 2;
    }

    conv_mfma5_kernel<<<dim3(T / 64, Bc), 256, 0, stream>>>(
        Au, wbA, Ccu, T, nullptr, nullptr, nullptr, 0, stR + 2 * SLOT);
    gnfin_kernel<<<(nbg + 63) / 64, 64, 0, stream>>>(stR + 2 * SLOT, st5, 1.f / (16.f * T), nbg);

    conv_mfma5_kernel<<<dim3(T / 64, Bc), 256, 0, stream>>>(
        Ccu, wbB, Bbu, T, st5, gd1a_g, gd1a_b, cpg1, stR + 3 * SLOT);
    gnfin_kernel<<<(nbg + 63) / 64, 64, 0, stream>>>(stR + 3 * SLOT, st6, 1.f / (16.f * T), nbg);

    // deres0: 4-way ci-split into Cc partials (Ccu dead now), then combine
    {
        float* pbuf = Cc;
        conv_epi7_kernel<<<dim3(T / 256, Bc, 4), 256, 0, stream>>>(
            Bbu, wt + wo.wd0, pbuf, T, Bc,
            st6, gd1b_g, gd1b_b, cpg1, Au);
        long tt = (long)Bc * 4 * T;
        epi_comb_kernel<<<nblk(tt), 256, 0, stream>>>(pbuf, bd0, out, T, Bc, tt);
    }
}

extern "C" void kernel_launch(void* const* d_in, const int* in_sizes, int n_in,
                              void* d_out, int out_size, void* d_ws, size_t ws_size,
                              hipStream_t stream) {
    const float* x = (const float*)d_in[0];
    const float* W[27];
    for (int i = 0; i < 27; ++i) W[i] = (const float*)d_in[i + 1];

    float* out = (float*)d_out;
    const WT wo = wt_offsets();

    // ws: [wT f32 | mfma bf16 | wn | wts | neg2 | stats(12 slots) | loss | vbest4 | vbj4 | bjs | A | B | C]
    const long WT_F32  = 262144;
    const long WB_F32  = 2 * 81920 / 2;        // 81920
    const long WTS_F32 = VQN_ * VQD_;          // 65536
    const long ST_F32  = 12 * 2048;
    const long VQ_F32  = 4 * PTS_ + 4 * PTS_ + PTS_;   // vbest4 + vbj4 + bjs
    const long FIXED = WT_F32 + WB_F32 + 1024 + WTS_F32 + 256 + ST_F32 + 64 + VQ_F32;
    int Bc = 0;
    for (int cand = B_; cand >= 1; cand >>= 1) {
        size_t need = ((size_t)FIXED + (size_t)3 * cand * C1_ * L_) * sizeof(float);
        if (need <= ws_size) { Bc = cand; break; }
    }
    if (Bc == 0) return;

    float* wt            = (float*)d_ws;
    unsigned short* wbA  = (unsigned short*)(wt + WT_F32);
    unsigned short* wbB  = wbA + 81920;
    float* wn            = wt + WT_F32 + WB_F32;
    float* wts           = wn + 1024;
    float* neg2          = wts + WTS_F32;
    float* st            = neg2 + 256;
    float* lossbuf       = st + ST_F32;
    float* vbest4        = lossbuf + 64;
    int*   vbj4          = (int*)(vbest4 + 4 * PTS_);
    int*   bjs           = vbj4 + 4 * PTS_;
    const long nbuf = (long)Bc * C1_ * L_;
    float* A  = (float*)(bjs + PTS_);
    float* Bb = A + nbuf;
    float* Cc = Bb + nbuf;

    const int D_ = C1_ / 2;

    auto prep = [&](const float* w, long off, int CO, int cig, int K,
                    int so, int si, int sk, int koff) {
        int total = cig * K * CO;
        wprep_kernel<<<(total + 255) / 256, 256, 0, stream>>>(
            w, wt + off, CO, cig, K, so, si, sk, koff);
    };
    prep(W[0],  wo.w0,   C1_, ORG_, 7, ORG_ * 7, 7,        1,  0);
    prep(W[3],  wo.wxa,  D_,  C1_,  1, C1_,      1,        1,  0);
    prep(W[6],  wo.wxb,  D_,  2,    5, 2 * 5,    5,        1,  0);
    prep(W[9],  wo.wxc,  C1_, D_,   1, D_,       1,        1,  0);
    prep(W[12], wo.w2,   C2_, C1_,  3, C1_ * 3,  3,        1,  0);
    prep(W[16], wo.wd2,  C1_, C2_,  3, 3,        C1_ * 3, -1,  2);
    prep(W[25], wo.wd0,  ORG_, C1_, 7, 7,        ORG_ * 7, -1, 6);
    wprep_mfma_kernel<<<81920 / 256, 256, 0, stream>>>(W[19], wbA);  // wd1a
    wprep_mfma_kernel<<<81920 / 256, 256, 0, stream>>>(W[22], wbB);  // wd1b
    wnorm_kernel<<<(VQN_ + 255) / 256, 256, 0, stream>>>(W[15], wn);
    // scores weights: 4 slices of 256 codes, wts[i*256 + o] = embed[o*64 + i]
    for (int q = 0; q < 4; ++q) {
        wprep_kernel<<<(256 * VQD_ + 255) / 256, 256, 0, stream>>>(
            W[15] + (long)q * 256 * VQD_, wts + (long)q * 256 * VQD_,
            256, VQD_, 1, VQD_, 1, 1, 0);
    }
    fill_kernel<<<1, 256, 0, stream>>>(neg2, -2.f, 256);

    zero_kernel<<<1, 1, 0, stream>>>(lossbuf);

    for (int b0 = 0; b0 < B_; b0 += Bc) {
        const float* xc = x + (long)b0 * ORG_ * L_;
        float* outc = out + (long)b0 * ORG_ * L_;
        run_chunk(xc, W, wt, wo, wbA, wbB, wn, wts, neg2, vbest4, vbj4, bjs,
                  outc, A, Bb, Cc, st, lossbuf, Bc, nbuf, stream);
    }

    {
        float invNP = 1.f / (float)(B_ * (L_ / 4));  // N = 65536
        finalize_kernel<<<1, 1, 0, stream>>>(lossbuf, out, invNP, (long)out_size - 2);
    }
}